// Round 10
// baseline (353.741 us; speedup 1.0000x reference)
//
#include <hip/hip_runtime.h>

typedef unsigned short u16;
typedef _Float16  f16x8  __attribute__((ext_vector_type(8)));
typedef _Float16  f16x4  __attribute__((ext_vector_type(4)));
typedef float     f32x4  __attribute__((ext_vector_type(4)));

#define MFMA_F16(a,b,c)  __builtin_amdgcn_mfma_f32_16x16x32_f16(a,b,c,0,0,0)

#define NTOK 64
#define DIM_ 128
#define SCALE_ 0.17677669529663687f   // 32^-0.5

// LDS geometry (u16 units) — R8 layout (54272 B, low-conflict strides)
#define HREG 6784      // per-head: q[64][36] | k[64][36] | vT[32][68]
#define KOFF 2304      // 64*36
#define VOFF 4608      // 2*64*36
#define SQK  36        // q/k stride (72-B rows, 8-B aligned)
#define SP   72        // P stride (144-B rows, 16-B aligned); 64*72=4608 exact over q+k
#define SAO  40        // attn-out stride (80-B rows, 16-B aligned)
#define SVT  68        // vT stride (136-B rows, 8-B aligned)
#define SMEM_U16 27136 // 4*HREG = 54272 B

__device__ __forceinline__ u16 f2h_u(float x) {
    _Float16 h = (_Float16)x;
    return __builtin_bit_cast(u16, h);
}

// ---------------- prep: repack f32 weights into fp16 MFMA B-fragment order ----------------
// ws: u16 frags [192 * 512]: [wq 0..31 | wkv 32..95 | wq_f 96..127 | wkv_f(k-half) 128..159 | wproj 160..191]
__global__ void wja_prep(const float* __restrict__ wq, const float* __restrict__ wkv,
                         const float* __restrict__ wq_f, const float* __restrict__ wkv_f,
                         const float* __restrict__ wproj, u16* __restrict__ ws)
{
    const int blk = blockIdx.x;
    const int l = threadIdx.x;          // 64 threads
    const float* W; int ldw, colbase;
    if (blk < 32)       { W = wq;    ldw = 128; colbase = (blk      >> 2) * 16; }
    else if (blk < 96)  { W = wkv;   ldw = 256; colbase = ((blk- 32) >> 2) * 16; }
    else if (blk < 128) { W = wq_f;  ldw = 128; colbase = ((blk- 96) >> 2) * 16; }
    else if (blk < 160) { W = wkv_f; ldw = 256; colbase = ((blk-128) >> 2) * 16; }
    else                { W = wproj; ldw = 128; colbase = ((blk-160) >> 2) * 16; }
    const int ks = blk & 3;
    const int m = l & 15, g = l >> 4;
    u16* dst = ws + blk * 512 + l * 8;
    #pragma unroll
    for (int i = 0; i < 8; ++i)
        dst[i] = f2h_u(W[(size_t)(32*ks + 8*g + i) * ldw + colbase + m]);
}

// ---------------- fused window joint attention, 8-wave version ----------------
// 1 block = 1 window; 512 threads = 8 waves. LDS 54272 B -> 2 blocks/CU (128KB
// usable, R8/R9 evidence) x 8 waves = 16 waves/CU = 4/SIMD (was 2/SIMD at R8).
// Staging: rt=w&3 rowtile, half=w>>2: half0 -> q (+vT lct0-3), half1 -> k (+vT lct4-7).
// Attention: h=w&3 head, qh=w>>2 query-half (rows [32qh,32qh+32)).
// Proj: wave w -> output cols [16w,16w+16).
__global__ __launch_bounds__(512, 2)
void wja_fused(
    const float* __restrict__ x, const float* __restrict__ f,
    const float* __restrict__ bq, const float* __restrict__ bkv,
    const float* __restrict__ bq_f, const float* __restrict__ bkv_f,
    const float* __restrict__ bproj, const float* __restrict__ btab,
    const u16* __restrict__ ws, float* __restrict__ out)
{
    __shared__ __align__(16) u16 smem[SMEM_U16];
    const int b    = blockIdx.x;
    const int tid  = threadIdx.x;
    const int w    = tid >> 6;
    const int lane = tid & 63;
    const int g    = lane >> 4;
    const int c    = lane & 15;
    const int rt   = w & 3;      // staging rowtile / attention head
    const int half = w >> 2;     // staging half / query-half
    const f32x4 zf4 = {0.f, 0.f, 0.f, 0.f};

    u16* const hb = smem + rt * HREG;   // head region (attention phases use h = rt)

    const float* const xb = x + (size_t)b * (NTOK * DIM_);
    const float* const fb = f + (size_t)b * (NTOK * DIM_);

    auto ldf16 = [](const float* p) -> f16x8 {
        f16x8 r;
        #pragma unroll
        for (int i = 0; i < 8; ++i) r[i] = (_Float16)p[i];
        return r;
    };
    // 8 fp16 from LDS at 8-B alignment: two b64
    auto ldlds8 = [](const u16* p) -> f16x8 {
        struct P2 { f16x4 lo, hi; } t;
        t.lo = *(const f16x4*)p;
        t.hi = *(const f16x4*)(p + 4);
        return __builtin_bit_cast(f16x8, t);
    };

    // ---- prefetch both paths' A-frags for rowtile rt ----
    f16x8 xfr[4], ffr[4];
    #pragma unroll
    for (int ks = 0; ks < 4; ++ks) {
        xfr[ks] = ldf16(xb + (16*rt + c) * DIM_ + 32*ks + 8*g);
        ffr[ks] = ldf16(fb + (16*rt + c) * DIM_ + 32*ks + 8*g);
    }

    // stage-A GEMM for rowtile rt, cols [16*lct0, 16*lctN):
    // which: 0 -> q area; 1 -> k area; 2 -> vT (transposed)
    auto gemmA = [&](const f16x8* afr, int wbase, const float* biasv, int which,
                     int lct0, int lctN) {
        for (int lct = lct0; lct < lctN; ++lct) {
            f32x4 acc = zf4;
            #pragma unroll
            for (int ks = 0; ks < 4; ++ks) {
                f16x8 bfr = *(const f16x8*)(ws + (wbase + 4*lct + ks) * 512 + lane * 8);
                acc = MFMA_F16(afr[ks], bfr, acc);
            }
            float bv = biasv[16*lct + c];
            const int hh = lct >> 1;
            const int cc = ((lct & 1) << 4) + c;
            #pragma unroll
            for (int i = 0; i < 4; ++i) {
                int row = 16*rt + 4*g + i;
                u16 vv = f2h_u(acc[i] + bv);
                if (which == 0)      smem[hh*HREG + row*SQK + cc] = vv;
                else if (which == 1) smem[hh*HREG + KOFF + row*SQK + cc] = vv;
                else                 smem[hh*HREG + VOFF + cc*SVT + row] = vv;
            }
        }
    };

    // ---- stage x-path ----
    if (half == 0) {
        gemmA(xfr,   0, bq,        0, 0, 8);   // q rowtile rt
        gemmA(xfr,  64, bkv + 128, 2, 0, 4);   // vT heads 0-1
    } else {
        gemmA(xfr,  32, bkv,       1, 0, 8);   // k rowtile rt
        gemmA(xfr,  64, bkv + 128, 2, 4, 8);   // vT heads 2-3
    }
    __syncthreads();                                             // (1)

    // ---- S = q k^T : head rt, query rows [32*half, 32*half+32) ----
    f32x4 S[2][4];
    {
        f16x8 qfr[2], kfr[4];
        #pragma unroll
        for (int t = 0; t < 2; ++t)
            qfr[t] = ldlds8(hb + (32*half + 16*t + c) * SQK + 8*g);
        #pragma unroll
        for (int t = 0; t < 4; ++t)
            kfr[t] = ldlds8(hb + KOFF + (16*t + c) * SQK + 8*g);
        #pragma unroll
        for (int mt = 0; mt < 2; ++mt)
            #pragma unroll
            for (int nt = 0; nt < 4; ++nt)
                S[mt][nt] = MFMA_F16(qfr[mt], kfr[nt], zf4);
    }
    __syncthreads();                                             // (2) q/k reads done

    // ---- stage f-path over q/k ----
    if (half == 0) gemmA(ffr,  96, bq_f,  0, 0, 8);   // q_f
    else           gemmA(ffr, 128, bkv_f, 1, 0, 8);   // k_f
    __syncthreads();                                             // (3)

    // ---- Sf fused with joint modulation ----
    {
        f16x8 kfr[4];
        #pragma unroll
        for (int t = 0; t < 4; ++t)
            kfr[t] = ldlds8(hb + KOFF + (16*t + c) * SQK + 8*g);
        #pragma unroll
        for (int mt = 0; mt < 2; ++mt) {
            f16x8 qfr = ldlds8(hb + (32*half + 16*mt + c) * SQK + 8*g);
            #pragma unroll
            for (int nt = 0; nt < 4; ++nt) {
                f32x4 sf = MFMA_F16(qfr, kfr[nt], zf4);
                int j = 16*nt + c;
                #pragma unroll
                for (int i = 0; i < 4; ++i) {
                    int r = 32*half + 16*mt + 4*g + i;
                    int idx = ((r >> 3) - (j >> 3) + 7) * 15 + ((r & 7) - (j & 7) + 7);
                    float bv = btab[idx * 4 + rt];
                    S[mt][nt][i] = (S[mt][nt][i] * SCALE_ + bv) * (sf[i] * SCALE_ + bv);
                }
            }
        }
    }

    // ---- softmax over rows (rows live in 16-lane groups x 4 nt) ----
    float rinv[2][4];
    #pragma unroll
    for (int mt = 0; mt < 2; ++mt)
        #pragma unroll
        for (int i = 0; i < 4; ++i) {
            float m = fmaxf(fmaxf(S[mt][0][i], S[mt][1][i]), fmaxf(S[mt][2][i], S[mt][3][i]));
            #pragma unroll
            for (int d = 1; d < 16; d <<= 1) m = fmaxf(m, __shfl_xor(m, d));
            float s0 = 0.f;
            #pragma unroll
            for (int nt = 0; nt < 4; ++nt) {
                float e = __expf(S[mt][nt][i] - m);
                S[mt][nt][i] = e;
                s0 += e;
            }
            #pragma unroll
            for (int d = 1; d < 16; d <<= 1) s0 += __shfl_xor(s0, d);
            rinv[mt][i] = 1.0f / s0;
        }
    __syncthreads();                                             // (4) qf/kf reads done (partner too)

    // ---- P (fp16) -> rows [32*half..+32), stride 72 over q+k region ----
    #pragma unroll
    for (int mt = 0; mt < 2; ++mt)
        #pragma unroll
        for (int nt = 0; nt < 4; ++nt)
            #pragma unroll
            for (int i = 0; i < 4; ++i)
                hb[(32*half + 16*mt + 4*g + i) * SP + 16*nt + c] = f2h_u(S[mt][nt][i] * rinv[mt][i]);

    // ---- O = P @ v (own rows; vT shared read-only) ----
    f32x4 O[2][2] = { { zf4, zf4 }, { zf4, zf4 } };
    #pragma unroll
    for (int ks = 0; ks < 2; ++ks) {
        f16x8 pfr[2], vfr[2];
        #pragma unroll
        for (int mt = 0; mt < 2; ++mt)
            pfr[mt] = *(const f16x8*)(hb + (32*half + 16*mt + c) * SP + 32*ks + 8*g);  // 16-B aligned
        #pragma unroll
        for (int nt = 0; nt < 2; ++nt)
            vfr[nt] = ldlds8(hb + VOFF + (16*nt + c) * SVT + 32*ks + 8*g);
        #pragma unroll
        for (int mt = 0; mt < 2; ++mt)
            #pragma unroll
            for (int nt = 0; nt < 2; ++nt)
                O[mt][nt] = MFMA_F16(pfr[mt], vfr[nt], O[mt][nt]);
    }
    __syncthreads();                                             // (5) all PV reads done before overlay

    // ---- attn-out (fp16) -> head base, [64][40], own rows ----
    #pragma unroll
    for (int mt = 0; mt < 2; ++mt)
        #pragma unroll
        for (int nt = 0; nt < 2; ++nt)
            #pragma unroll
            for (int i = 0; i < 4; ++i)
                hb[(32*half + 16*mt + 4*g + i) * SAO + 16*nt + c] = f2h_u(O[mt][nt][i]);
    __syncthreads();                                             // (6)

    // ---- proj: wave w -> output cols [16w, 16w+16), K=128 over 4 source heads ----
    f32x4 PO[4] = { zf4, zf4, zf4, zf4 };
    #pragma unroll
    for (int ks = 0; ks < 4; ++ks) {
        const u16* ao = smem + ks * HREG;
        f16x8 bfr = *(const f16x8*)(ws + (160 + w * 4 + ks) * 512 + lane * 8);
        #pragma unroll
        for (int mt = 0; mt < 4; ++mt) {
            f16x8 afr = *(const f16x8*)(ao + (16*mt + c) * SAO + 8*g);   // 16-B aligned
            PO[mt] = MFMA_F16(afr, bfr, PO[mt]);
        }
    }
    __syncthreads();                                             // (7) before FIN overlay

    // FIN f32 [64][132] overlays smem bytes [0, 33792)
    float* const fin = (float*)smem;
    {
        float bv = bproj[16*w + c];
        #pragma unroll
        for (int mt = 0; mt < 4; ++mt)
            #pragma unroll
            for (int i = 0; i < 4; ++i)
                fin[(16*mt + 4*g + i) * 132 + 16*w + c] = PO[mt][i] + bv;
    }
    __syncthreads();                                             // (8)

    // ---- coalesced f32 store: 64 rows x 128 cols, 512 threads ----
    {
        const int row = tid >> 3, cb = (tid & 7) * 16;
        float* gout = out + (size_t)b * 8192 + row * 128 + cb;
        const float* src = fin + row * 132 + cb;
        #pragma unroll
        for (int q2 = 0; q2 < 4; ++q2)
            *(f32x4*)(gout + q2 * 4) = *(const f32x4*)(src + q2 * 4);
    }
}

extern "C" void kernel_launch(void* const* d_in, const int* in_sizes, int n_in,
                              void* d_out, int out_size, void* d_ws, size_t ws_size,
                              hipStream_t stream)
{
    const float* x     = (const float*)d_in[0];
    const float* f     = (const float*)d_in[1];
    const float* wq    = (const float*)d_in[2];
    const float* bq    = (const float*)d_in[3];
    const float* wkv   = (const float*)d_in[4];
    const float* bkv   = (const float*)d_in[5];
    const float* wq_f  = (const float*)d_in[6];
    const float* bq_f  = (const float*)d_in[7];
    const float* wkv_f = (const float*)d_in[8];
    const float* bkv_f = (const float*)d_in[9];
    const float* btab  = (const float*)d_in[10];
    const float* wproj = (const float*)d_in[11];
    const float* bproj = (const float*)d_in[12];
    u16* ws    = (u16*)d_ws;
    float* out = (float*)d_out;

    hipLaunchKernelGGL(wja_prep, dim3(192), dim3(64), 0, stream,
                       wq, wkv, wq_f, wkv_f, wproj, ws);
    hipLaunchKernelGGL(wja_fused, dim3(4096), dim3(512), 0, stream,
                       x, f, bq, bkv, bq_f, bkv_f, bproj, btab, ws, out);
}